// Round 5
// baseline (13259.412 us; speedup 1.0000x reference)
//
#include <hip/hip_runtime.h>
#include <hip/hip_bf16.h>

// ---------------------------------------------------------------------------
// Decoder_20435454395154  — round 8
// k3: dual-recurrence phase interleave to hide the cross-CU exchange.
//   * 2 blocks x 512 threads (8 waves = 2 waves/EU -> real TLP; r7's 1/EU
//     exposed every latency serially). Block dd owns dim half; BOTH
//     independent batch-half recurrences run in the same block as
//     alternating phases A (batches 0-15) and B (16-31).
//   * Exchange is pairwise (1 peer). Ring loads for half X step t-1 are
//     ISSUED one phase (~500 cyc) before they are CHECKED, so the MALL
//     round trip hides under the other half's MFMA+gates. Tagged-retry
//     (same self-validating u32 scheme) only fires on skew.
//   * Registers: Bf[4][8] pinned (128) + ~80 live; W_ih slice lives in LDS
//     (64 KB, 2 ds_read_b128/phase) to stay under the 256-reg budget from
//     amdgpu_waves_per_eu(2,2). LDS total 99 KB also caps 1 block/CU.
//   * Skew bound: publish X(t) requires consuming X(t-1) -> |skew| <= 1;
//     ring depth 4; every u32 tagged (torn/poison safe).
// ---------------------------------------------------------------------------

typedef float  f32x4 __attribute__((ext_vector_type(4)));
typedef short  s16x8 __attribute__((ext_vector_type(8)));

__device__ __forceinline__ unsigned short f2bf(float f) {
  union { float f; unsigned u; } v; v.f = f;
  unsigned r = v.u + 0x7FFFu + ((v.u >> 16) & 1u);   // RNE
  return (unsigned short)(r >> 16);
}

#define SEQ_   3072
#define TAGBAD(v0, v1, tg) \
  ((((((unsigned)(v0)) ^ (tg)) | (((unsigned)((v0) >> 32)) ^ (tg)) | \
     (((unsigned)(v1)) ^ (tg)) | (((unsigned)((v1) >> 32)) ^ (tg))) >> 16) != 0)

// ------------------------------- prologue ----------------------------------

__global__ void p0_norms(const float* __restrict__ v_ih, const float* __restrict__ g_ih,
                         const float* __restrict__ v_hh, const float* __restrict__ g_hh,
                         float* __restrict__ rsih, float* __restrict__ rshh) {
  const int w = (blockIdx.x * 256 + threadIdx.x) >> 6;
  const int lane = threadIdx.x & 63;
  if (w < 1024) {
    float v = v_ih[w * 64 + lane];
    float s = v * v;
    #pragma unroll
    for (int o = 32; o > 0; o >>= 1) s += __shfl_xor(s, o);
    if (lane == 0) rsih[w] = g_ih[w] * rsqrtf(s);
  } else {
    const int r = w - 1024;
    f32x4 v = *(const f32x4*)(v_hh + (size_t)r * 256 + lane * 4);
    float s = v[0]*v[0] + v[1]*v[1] + v[2]*v[2] + v[3]*v[3];
    #pragma unroll
    for (int o = 32; o > 0; o >>= 1) s += __shfl_xor(s, o);
    if (lane == 0) rshh[r] = g_hh[r] * rsqrtf(s);
  }
}

// pack W_hh into B-fragment order: [sq(16)][g(4)][ks(8)][lane(64)][8]
__global__ void p2_packWB(const float* __restrict__ v_hh, const float* __restrict__ rshh,
                          unsigned short* __restrict__ WBp) {
  const int o = blockIdx.x * 256 + threadIdx.x;
  const int j = o & 7, l = (o >> 3) & 63, ks = (o >> 9) & 7, g = (o >> 12) & 3, sq = o >> 14;
  const int r = g * 256 + (sq >> 1) * 32 + (sq & 1) * 16 + (l & 15);
  const int k = ks * 32 + (l >> 4) * 8 + j;
  WBp[o] = f2bf(v_hh[(size_t)r * 256 + k] * rshh[r]);
}

// pack W_ih: [sq(16)][g(4)][ks(2)][lane(64)][8]
__global__ void p3_packWI(const float* __restrict__ v_ih, const float* __restrict__ rsih,
                          unsigned short* __restrict__ WIp) {
  const int o = blockIdx.x * 256 + threadIdx.x;
  const int j = o & 7, l = (o >> 3) & 63, ks = (o >> 9) & 1, g = (o >> 10) & 3, sq = o >> 12;
  const int r = g * 256 + (sq >> 1) * 32 + (sq & 1) * 16 + (l & 15);
  const int k = ks * 32 + (l >> 4) * 8 + j;
  WIp[o] = f2bf(v_ih[(size_t)r * 64 + k] * rsih[r]);
}

__global__ void k1a_cond(const float* __restrict__ z, const float* __restrict__ theta,
                         const float* __restrict__ W_theta, const float* __restrict__ b_theta,
                         float* __restrict__ cond) {
  const int i = blockIdx.x * 256 + threadIdx.x;
  const int b = i >> 8, n = i & 255;
  cond[i] = z[i] + theta[b*2+0] * W_theta[n*2+0] + theta[b*2+1] * W_theta[n*2+1] + b_theta[n];
}

__global__ __launch_bounds__(256) void k1b_dec(const float* __restrict__ cond,
                                               const float* __restrict__ W_dec,
                                               const float* __restrict__ b_dec,
                                               float* __restrict__ x) {
  const int r = blockIdx.x * 256 + threadIdx.x;
  float acc[32];
  const float bd = b_dec[r];
  #pragma unroll
  for (int b = 0; b < 32; ++b) acc[b] = bd;
  const f32x4* wp = (const f32x4*)(W_dec + (size_t)r * 256);
  for (int k4 = 0; k4 < 64; ++k4) {
    const f32x4 w = wp[k4];
    #pragma unroll
    for (int b = 0; b < 32; ++b) {
      const float* cp = cond + b * 256 + k4 * 4;
      acc[b] += w[0]*cp[0] + w[1]*cp[1] + w[2]*cp[2] + w[3]*cp[3];
    }
  }
  #pragma unroll
  for (int b = 0; b < 32; ++b) x[(size_t)b * 65536 + r] = acc[b];
}

__global__ void k1c_gnstats(const float* __restrict__ x, const float* __restrict__ gn_w,
                            const float* __restrict__ gn_b,
                            float* __restrict__ gnA, float* __restrict__ gnB) {
  __shared__ float sS[256], sQ[256];
  const int b = blockIdx.x >> 3, g = blockIdx.x & 7;
  const float* xp = x + (size_t)b * 65536 + g * 8192;
  float s = 0.f, qq = 0.f;
  for (int i = threadIdx.x; i < 8192; i += 256) { float v = xp[i]; s += v; qq += v * v; }
  sS[threadIdx.x] = s; sQ[threadIdx.x] = qq; __syncthreads();
  for (int o = 128; o > 0; o >>= 1) {
    if (threadIdx.x < o) { sS[threadIdx.x] += sS[threadIdx.x+o]; sQ[threadIdx.x] += sQ[threadIdx.x+o]; }
    __syncthreads();
  }
  if (threadIdx.x < 8) {
    const float mu  = sS[0] * (1.f / 8192.f);
    const float var = sQ[0] * (1.f / 8192.f) - mu * mu;
    const float rstd = rsqrtf(var + 1e-5f);
    const int c = g * 8 + threadIdx.x;
    const float a = gn_w[c] * rstd;
    gnA[b*64+c] = a; gnB[b*64+c] = gn_b[c] - mu * a;
  }
}

__global__ void k1d_inp(const float* __restrict__ x, const float* __restrict__ gnA,
                        const float* __restrict__ gnB, const float* __restrict__ emb,
                        const int* __restrict__ xt, unsigned short* __restrict__ inp) {
  __shared__ float xT[128 * 65];
  const int b = blockIdx.x >> 3, pt = blockIdx.x & 7, p0 = pt * 128;
  const int tid = threadIdx.x;
  for (int i = tid; i < 8192; i += 256) {
    const int p = i & 127, ch = i >> 7;
    float v = x[(size_t)b * 65536 + ch * 1024 + p0 + p];
    xT[p * 65 + ch] = v * gnA[b*64+ch] + gnB[b*64+ch];
  }
  __syncthreads();
  const int wave = tid >> 6, lane = tid & 63;
  for (int row = wave; row < 384; row += 4) {
    const int c3 = row / 128, p = row % 128;
    const int t = c3 * 1024 + p0 + p;
    float v = xT[p * 65 + lane];
    if (t > 0) {
      const int tok = xt[b * SEQ_ + t - 1];
      v += emb[tok * 64 + lane];
    }
    inp[((size_t)b * SEQ_ + t) * 64 + lane] = f2bf(v);
  }
}

// ------------------------------- recurrence --------------------------------
// 2 blocks x 512 threads, block dd = dim half. Wave w owns slice sq=dd*8+w.
// Phases: A = batches 0-15, B = batches 16-31 (independent recurrences).
__global__ __launch_bounds__(512)
__attribute__((amdgpu_waves_per_eu(2, 2)))
void k3_lstm(
    const unsigned short* __restrict__ WBp, const unsigned short* __restrict__ WIp,
    const unsigned short* __restrict__ inp, const float* __restrict__ b_ih,
    const float* __restrict__ b_hh, unsigned short* __restrict__ hs,
    unsigned long long* __restrict__ ring64) {
  const int dd = blockIdx.x;                  // dim half 0,1
  const int peer = 1 - dd;
  const int tid = threadIdx.x;
  const int w = tid >> 6, lane = tid & 63;
  const int col = lane & 15, quad = lane >> 4;
  const int sq = dd * 8 + w;                  // global 16-dim slice
  const int mydim = sq * 16 + col;

  __shared__ unsigned short hbuf[2][2][16][264]; // [half A/B][parity][batch][dim+pad]
  __shared__ unsigned short WIl[8 * 4 * 2 * 64 * 8]; // [w][g][ks][lane][8] = 64KB

  // stage this block's W_ih slices into LDS (frees 32 VGPRs/wave)
  for (int i = tid; i < 4096; i += 512) {
    const int l = i & 63, ks = (i >> 6) & 1, g = (i >> 7) & 3, ww = i >> 9;
    ((s16x8*)WIl)[i] = ((const s16x8*)WIp)[(((dd * 8 + ww) * 4 + g) * 2 + ks) * 64 + l];
  }

  // ---- resident W_hh fragments (pinned; budget 256/wave via waves_per_eu) --
  s16x8 Bf[4][8];
  #pragma unroll
  for (int g = 0; g < 4; ++g)
    #pragma unroll
    for (int ks = 0; ks < 8; ++ks) {
      Bf[g][ks] = ((const s16x8*)WBp)[((sq * 4 + g) * 8 + ks) * 64 + lane];
      asm volatile("" : "+v"(Bf[g][ks]));
    }
  float bias[4];
  #pragma unroll
  for (int g = 0; g < 4; ++g) {
    const int n = g * 256 + sq * 16 + col;
    bias[g] = b_ih[n] + b_hh[n];
  }
  __syncthreads();   // WIl ready

  float cA[4] = {0.f, 0.f, 0.f, 0.f};
  float cB[4] = {0.f, 0.f, 0.f, 0.f};

  const unsigned short* ipA = inp + (size_t)col * SEQ_ * 64 + quad * 8;         // b 0-15
  const unsigned short* ipB = inp + (size_t)(16 + col) * SEQ_ * 64 + quad * 8;  // b 16-31
  unsigned short* hsA = hs + (size_t)sq * 512 + (size_t)(quad * 4) * 16 + col;
  unsigned short* hsB = hsA + 256;   // +16 batches * 16

  // ring regions: ((rs*2 + half)*2 + srcdd) * 1024 u64; [dim(128)][batch(16)] u32
  const int wrOff = (w * 16 + col) * 8 + quad * 2;
  const int pd = tid >> 2, jb = tid & 3;
  const int rdOff = pd * 8 + jb * 2;
  const int pdim = peer * 128 + pd;
  const int pb0 = jb * 4;

  unsigned long long infA0 = 0, infA1 = 0, infB0 = 0, infB1 = 0;

  // prime A-input for t=0
  s16x8 aA0 = *(const s16x8*)(ipA);
  s16x8 aA1 = *(const s16x8*)(ipA + 32);

  for (int t = 0; t < SEQ_; ++t) {
    const int rs = (t - 1) & 3, par = t & 1, pr = (t - 1) & 1;
    const unsigned tagIn  = (0x5000u | (unsigned)(t - 1)) << 16;
    const unsigned tagOut = (0x5000u | (unsigned)t) << 16;

    // ===================== PHASE A (batches 0-15) =====================
    // early-issue this step's B input (consumed one phase later)
    s16x8 aB0 = *(const s16x8*)(ipB + (size_t)t * 64);
    s16x8 aB1 = *(const s16x8*)(ipB + (size_t)t * 64 + 32);

    if (t > 0) {
      // infA issued mid-phase-B of step t-1 (~1 phase in flight)
      const unsigned long long* rpA =
          ring64 + (size_t)((rs * 2 + 0) * 2 + peer) * 1024 + rdOff;
      unsigned long long v0 = infA0, v1 = infA1;
      while (TAGBAD(v0, v1, tagIn)) {
        v0 = __hip_atomic_load(rpA + 0, __ATOMIC_RELAXED, __HIP_MEMORY_SCOPE_SYSTEM);
        v1 = __hip_atomic_load(rpA + 1, __ATOMIC_RELAXED, __HIP_MEMORY_SCOPE_SYSTEM);
      }
      hbuf[0][pr][pb0 + 0][pdim] = (unsigned short)v0;
      hbuf[0][pr][pb0 + 1][pdim] = (unsigned short)(v0 >> 32);
      hbuf[0][pr][pb0 + 2][pdim] = (unsigned short)v1;
      hbuf[0][pr][pb0 + 3][pdim] = (unsigned short)(v1 >> 32);
      __syncthreads();
    }

    f32x4 acc[4];
    #pragma unroll
    for (int g = 0; g < 4; ++g) acc[g] = (f32x4){bias[g], bias[g], bias[g], bias[g]};
    #pragma unroll
    for (int g = 0; g < 4; ++g) {
      const s16x8 wi0 = ((const s16x8*)WIl)[((w * 4 + g) * 2 + 0) * 64 + lane];
      const s16x8 wi1 = ((const s16x8*)WIl)[((w * 4 + g) * 2 + 1) * 64 + lane];
      acc[g] = __builtin_amdgcn_mfma_f32_16x16x32_bf16(aA0, wi0, acc[g], 0, 0, 0);
      acc[g] = __builtin_amdgcn_mfma_f32_16x16x32_bf16(aA1, wi1, acc[g], 0, 0, 0);
    }
    if (t > 0) {
      const unsigned short (*hb)[264] = hbuf[0][pr];
      #pragma unroll
      for (int ks = 0; ks < 8; ++ks) {
        const s16x8 a = *(const s16x8*)&hb[col][ks * 32 + quad * 8];
        #pragma unroll
        for (int g = 0; g < 4; ++g)
          acc[g] = __builtin_amdgcn_mfma_f32_16x16x32_bf16(a, Bf[g][ks], acc[g], 0, 0, 0);
      }
      // mid-A: issue ring loads for B(t-1) (published end of B(t-1))
      const unsigned long long* rpB =
          ring64 + (size_t)((rs * 2 + 1) * 2 + peer) * 1024 + rdOff;
      infB0 = __hip_atomic_load(rpB + 0, __ATOMIC_RELAXED, __HIP_MEMORY_SCOPE_SYSTEM);
      infB1 = __hip_atomic_load(rpB + 1, __ATOMIC_RELAXED, __HIP_MEMORY_SCOPE_SYSTEM);
    }

    {
      unsigned tg0, tg1, tg2, tg3;
      #pragma unroll
      for (int r = 0; r < 4; ++r) {
        const float gi = acc[0][r], gf = acc[1][r], gg = acc[2][r], go = acc[3][r];
        const float si = 1.f / (1.f + __expf(-gi));
        const float sf = 1.f / (1.f + __expf(-gf));
        const float tg_ = 2.f / (1.f + __expf(-2.f * gg)) - 1.f;
        const float so = 1.f / (1.f + __expf(-go));
        cA[r] = sf * cA[r] + si * tg_;
        const float tc = 2.f / (1.f + __expf(-2.f * cA[r])) - 1.f;
        const unsigned short h16 = f2bf(so * tc);
        hbuf[0][par][quad * 4 + r][mydim] = h16;
        hsA[(size_t)t * 8192 + r * 16] = h16;
        const unsigned tv = tagOut | h16;
        if (r == 0) tg0 = tv; else if (r == 1) tg1 = tv; else if (r == 2) tg2 = tv; else tg3 = tv;
      }
      unsigned long long* wp =
          ring64 + (size_t)(((t & 3) * 2 + 0) * 2 + dd) * 1024 + wrOff;
      __hip_atomic_store(wp + 0, (unsigned long long)tg0 | ((unsigned long long)tg1 << 32),
                         __ATOMIC_RELAXED, __HIP_MEMORY_SCOPE_SYSTEM);
      __hip_atomic_store(wp + 1, (unsigned long long)tg2 | ((unsigned long long)tg3 << 32),
                         __ATOMIC_RELAXED, __HIP_MEMORY_SCOPE_SYSTEM);
    }

    // ===================== PHASE B (batches 16-31) =====================
    // early-issue next step's A input
    {
      const int tn = (t + 1 < SEQ_) ? (t + 1) : t;
      aA0 = *(const s16x8*)(ipA + (size_t)tn * 64);
      aA1 = *(const s16x8*)(ipA + (size_t)tn * 64 + 32);
    }

    if (t > 0) {
      const unsigned long long* rpB =
          ring64 + (size_t)((rs * 2 + 1) * 2 + peer) * 1024 + rdOff;
      unsigned long long v0 = infB0, v1 = infB1;
      while (TAGBAD(v0, v1, tagIn)) {
        v0 = __hip_atomic_load(rpB + 0, __ATOMIC_RELAXED, __HIP_MEMORY_SCOPE_SYSTEM);
        v1 = __hip_atomic_load(rpB + 1, __ATOMIC_RELAXED, __HIP_MEMORY_SCOPE_SYSTEM);
      }
      hbuf[1][pr][pb0 + 0][pdim] = (unsigned short)v0;
      hbuf[1][pr][pb0 + 1][pdim] = (unsigned short)(v0 >> 32);
      hbuf[1][pr][pb0 + 2][pdim] = (unsigned short)v1;
      hbuf[1][pr][pb0 + 3][pdim] = (unsigned short)(v1 >> 32);
      __syncthreads();
    }

    #pragma unroll
    for (int g = 0; g < 4; ++g) acc[g] = (f32x4){bias[g], bias[g], bias[g], bias[g]};
    #pragma unroll
    for (int g = 0; g < 4; ++g) {
      const s16x8 wi0 = ((const s16x8*)WIl)[((w * 4 + g) * 2 + 0) * 64 + lane];
      const s16x8 wi1 = ((const s16x8*)WIl)[((w * 4 + g) * 2 + 1) * 64 + lane];
      acc[g] = __builtin_amdgcn_mfma_f32_16x16x32_bf16(aB0, wi0, acc[g], 0, 0, 0);
      acc[g] = __builtin_amdgcn_mfma_f32_16x16x32_bf16(aB1, wi1, acc[g], 0, 0, 0);
    }
    if (t > 0) {
      const unsigned short (*hb)[264] = hbuf[1][pr];
      #pragma unroll
      for (int ks = 0; ks < 8; ++ks) {
        const s16x8 a = *(const s16x8*)&hb[col][ks * 32 + quad * 8];
        #pragma unroll
        for (int g = 0; g < 4; ++g)
          acc[g] = __builtin_amdgcn_mfma_f32_16x16x32_bf16(a, Bf[g][ks], acc[g], 0, 0, 0);
      }
    }
    {
      // mid-B: issue ring loads for A(t) (published end of this step's A)
      const unsigned long long* rpA2 =
          ring64 + (size_t)(((t & 3) * 2 + 0) * 2 + peer) * 1024 + rdOff;
      infA0 = __hip_atomic_load(rpA2 + 0, __ATOMIC_RELAXED, __HIP_MEMORY_SCOPE_SYSTEM);
      infA1 = __hip_atomic_load(rpA2 + 1, __ATOMIC_RELAXED, __HIP_MEMORY_SCOPE_SYSTEM);
    }

    {
      unsigned tg0, tg1, tg2, tg3;
      #pragma unroll
      for (int r = 0; r < 4; ++r) {
        const float gi = acc[0][r], gf = acc[1][r], gg = acc[2][r], go = acc[3][r];
        const float si = 1.f / (1.f + __expf(-gi));
        const float sf = 1.f / (1.f + __expf(-gf));
        const float tg_ = 2.f / (1.f + __expf(-2.f * gg)) - 1.f;
        const float so = 1.f / (1.f + __expf(-go));
        cB[r] = sf * cB[r] + si * tg_;
        const float tc = 2.f / (1.f + __expf(-2.f * cB[r])) - 1.f;
        const unsigned short h16 = f2bf(so * tc);
        hbuf[1][par][quad * 4 + r][mydim] = h16;
        hsB[(size_t)t * 8192 + r * 16] = h16;
        const unsigned tv = tagOut | h16;
        if (r == 0) tg0 = tv; else if (r == 1) tg1 = tv; else if (r == 2) tg2 = tv; else tg3 = tv;
      }
      unsigned long long* wp =
          ring64 + (size_t)(((t & 3) * 2 + 1) * 2 + dd) * 1024 + wrOff;
      __hip_atomic_store(wp + 0, (unsigned long long)tg0 | ((unsigned long long)tg1 << 32),
                         __ATOMIC_RELAXED, __HIP_MEMORY_SCOPE_SYSTEM);
      __hip_atomic_store(wp + 1, (unsigned long long)tg2 | ((unsigned long long)tg3 << 32),
                         __ATOMIC_RELAXED, __HIP_MEMORY_SCOPE_SYSTEM);
    }
  }
}

// ------------------------------- readout -----------------------------------

// out[b,v,t] = hs[t,b,:] . W_ro[v,:] + b_ro[v]; hs in [t][slot16][b32][16] layout
__global__ __launch_bounds__(256, 1) void k4_outgemm(const unsigned short* __restrict__ ex,
                                                     const float* __restrict__ W_ro,
                                                     const float* __restrict__ b_ro,
                                                     float* __restrict__ out) {
  __shared__ unsigned short WroL[8 * 8 * 64 * 8];   // [slot=nt*8+ks][lane][8], 64KB
  const int tid = threadIdx.x, lane = tid & 63, wave = tid >> 6;
  const int bi = blockIdx.x;
  const int b = bi / 48; const int rem = bi % 48; const int tc = rem >> 1, nh = rem & 1;
  const int col = lane & 15, quad = lane >> 4;

  for (int slot = wave; slot < 64; slot += 4) {
    const int nt = slot >> 3, ks = slot & 7;
    const int v = nh * 128 + nt * 16 + col;
    const int k = ks * 32 + quad * 8;
    const float* src = W_ro + (size_t)v * 256 + k;
    s16x8 pk;
    #pragma unroll
    for (int j = 0; j < 8; ++j) pk[j] = (short)f2bf(src[j]);
    *((s16x8*)WroL + slot * 64 + lane) = pk;
  }
  __syncthreads();

  const int t0 = tc * 128 + wave * 32;
  f32x4 acc[2][8];
  #pragma unroll
  for (int mt = 0; mt < 2; ++mt)
    #pragma unroll
    for (int nt = 0; nt < 8; ++nt) acc[mt][nt] = (f32x4){0.f, 0.f, 0.f, 0.f};

  #pragma unroll
  for (int ks = 0; ks < 8; ++ks) {
    const int slot = 2 * ks + (quad >> 1), off = (quad & 1) * 8;
    const s16x8 a0 = *(const s16x8*)(ex + (((size_t)(t0 + col) * 16 + slot) * 32 + b) * 16 + off);
    const s16x8 a1 = *(const s16x8*)(ex + (((size_t)(t0 + 16 + col) * 16 + slot) * 32 + b) * 16 + off);
    #pragma unroll
    for (int nt = 0; nt < 8; ++nt) {
      const s16x8 bb = *((const s16x8*)WroL + (nt * 8 + ks) * 64 + lane);
      acc[0][nt] = __builtin_amdgcn_mfma_f32_16x16x32_bf16(a0, bb, acc[0][nt], 0, 0, 0);
      acc[1][nt] = __builtin_amdgcn_mfma_f32_16x16x32_bf16(a1, bb, acc[1][nt], 0, 0, 0);
    }
  }

  #pragma unroll
  for (int nt = 0; nt < 8; ++nt) {
    const int v = nh * 128 + nt * 16 + col;
    const float brv = b_ro[v];
    #pragma unroll
    for (int mt = 0; mt < 2; ++mt) {
      f32x4 o = acc[mt][nt];
      o[0] += brv; o[1] += brv; o[2] += brv; o[3] += brv;
      const int t = t0 + mt * 16 + quad * 4;
      *(f32x4*)(out + ((size_t)b * 256 + v) * SEQ_ + t) = o;
    }
  }
}

// ------------------------------- launcher ----------------------------------

extern "C" void kernel_launch(void* const* d_in, const int* in_sizes, int n_in,
                              void* d_out, int out_size, void* d_ws, size_t ws_size,
                              hipStream_t stream) {
  const float* z       = (const float*)d_in[0];
  const float* theta   = (const float*)d_in[1];
  const float* W_theta = (const float*)d_in[2];
  const float* b_theta = (const float*)d_in[3];
  const float* W_dec   = (const float*)d_in[4];
  const float* b_dec   = (const float*)d_in[5];
  const float* gn_w    = (const float*)d_in[6];
  const float* gn_b    = (const float*)d_in[7];
  const float* emb     = (const float*)d_in[8];
  const float* v_ih    = (const float*)d_in[9];
  const float* g_ih    = (const float*)d_in[10];
  const float* v_hh    = (const float*)d_in[11];
  const float* g_hh    = (const float*)d_in[12];
  const float* b_ih    = (const float*)d_in[13];
  const float* b_hh    = (const float*)d_in[14];
  const float* W_ro    = (const float*)d_in[15];
  const float* b_ro    = (const float*)d_in[16];
  const int*   x_tgt   = (const int*)d_in[17];
  float* out = (float*)d_out;
  char* ws = (char*)d_ws;

  // ws layout (bytes) — identical footprint to rounds 3-7 (proven to fit)
  float*              cond  = (float*)(ws + 0);                 //    32768
  float*              x     = (float*)(ws + 32768);             //  8388608
  float*              gnA   = (float*)(ws + 8421376);           //     8192
  float*              gnB   = (float*)(ws + 8429568);           //     8192
  float*              rsih  = (float*)(ws + 8437760);           //     4096
  float*              rshh  = (float*)(ws + 8441856);           //     4096
  unsigned short*     WIp   = (unsigned short*)(ws + 8445952);  //   131072
  unsigned short*     WBp   = (unsigned short*)(ws + 8577024);  //   524288
  unsigned short*     inp   = (unsigned short*)(ws + 9101312);  // 12582912
  unsigned short*     hs    = (unsigned short*)(ws + 21684224); // 50331648  [t][slot16][b32][16]
  unsigned long long* ring64= (unsigned long long*)(ws + 72015872); // 131072 (4rs x 2half x 2dd x 8KB tagged)
  if (ws_size < 72409088u) return;

  p0_norms  <<<512,  256, 0, stream>>>(v_ih, g_ih, v_hh, g_hh, rsih, rshh);
  p2_packWB <<<1024, 256, 0, stream>>>(v_hh, rshh, WBp);
  p3_packWI <<<256,  256, 0, stream>>>(v_ih, rsih, WIp);
  k1a_cond  <<<32,   256, 0, stream>>>(z, theta, W_theta, b_theta, cond);
  k1b_dec   <<<256,  256, 0, stream>>>(cond, W_dec, b_dec, x);
  k1c_gnstats<<<256, 256, 0, stream>>>(x, gn_w, gn_b, gnA, gnB);
  k1d_inp   <<<256,  256, 0, stream>>>(x, gnA, gnB, emb, x_tgt, inp);
  k3_lstm   <<<2,    512, 0, stream>>>(WBp, WIp, inp, b_ih, b_hh, hs, ring64);
  k4_outgemm<<<1536, 256, 0, stream>>>(hs, W_ro, b_ro, out);
}